// Round 8
// baseline (156.860 us; speedup 1.0000x reference)
//
#include <hip/hip_runtime.h>

// VQ-VAE quantizer, MI355X (gfx950). B=64, C=D=64, H=32, W=32 -> N=65536 tokens, K=1024 codes.
// Round 8: argmin restructured to the m97 LDS-staged shape. R7 post-mortem: argmin was
// stall-bound on per-wave B-fragment L2 streaming (MfmaUtil 18.5, VALUBusy 22, Occ 19 --
// all idle; R5 no-prefetch 97us vs R7 1-deep 51us tracks load latency, not MFMA).
//   argmin: 512 blocks x 512 thr. Block = 128 tokens; wave = 16 tokens (1 MFMA group).
//           All 8 waves share one B chunk staged per block into LDS via global_load_lds
//           (double-buffered, 1 barrier/chunk; __syncthreads' vmcnt(0) drain = correctness).
//           k-loop VMEM per wave: ZERO (ds_read_b128 only). Token-split => no K-merge.
//           MFMA floor 12.4us (1.57M MFMA / 256 CU x 4.85 cyc).
//   prep/output/finalize: R7-verbatim (proven).
// Distance math bit-identical to R4..R7 (absmax 2.394531): 3-product split-bf16, same
// MFMA order, ascending-chunk strict-> ties, lowest-code-on-tie cross-lane.
// Outputs (flat): z_q [4194304] f32 NCHW, loss [1], perplexity [1].

typedef __attribute__((ext_vector_type(8))) short short8;   // 8 bf16 (4 VGPRs)
typedef __attribute__((ext_vector_type(4))) float float4v;  // MFMA C/D frag

#define NELEM 4194304

// ---- workspace layout (bytes) ----
#define WS_CBF   0        // ushort[131072]: packed split-bf16 codebook, B-frag order (256 KB)
#define WS_C2H   262144   // f32 c2h[1024] = -0.5*||c||^2
#define WS_HIST  266240   // i32 hist[1024]
#define WS_LOSS  270336   // f32 loss_part[64]
#define WS_IDX   270592   // i32 idx[65536]
// zs (split-bf16 z, 16,777,216 B) lives in d_out (16,777,224 B): consumed by argmin,
// then overwritten by output_kernel (stream-ordered).

__device__ __forceinline__ unsigned bf16_rne(float x) {
    unsigned u = __float_as_uint(x);
    return (u + 0x7fffu + ((u >> 16) & 1u)) >> 16;
}

__device__ __forceinline__ void gl_lds16(const void* g, void* l) {
    // async global->LDS DMA, 16B/lane; LDS dst = uniform base + lane*16 (HW scatter)
    __builtin_amdgcn_global_load_lds(
        (const __attribute__((address_space(1))) unsigned*)g,
        (__attribute__((address_space(3))) unsigned*)l, 16, 0, 0);
}

// zs layout (short8 units): id = (((gg*2 + st)*4 + quad)*2 + split)*16 + col
// cbf layout (bytes): (chunk*4 + fid)*1024 + lane*16, fid = split*2 + st.

// grid = 1092 blocks x 256 (R7-verbatim):
//   0..1023 zsplit; 1024..1087 pack codebook chunk + c2; 1088..1091 zero hist/loss.
__global__ __launch_bounds__(256) void prep_kernel(
    const float* __restrict__ z, const float* __restrict__ cb,
    ushort* __restrict__ zs, ushort* __restrict__ cbf, float* __restrict__ c2h,
    int* __restrict__ hist, float* __restrict__ loss_part)
{
    __shared__ float s_c2[2][16];
    int tid  = threadIdx.x;
    int lane = tid & 63, wave = tid >> 6;
    int quad = lane >> 4, col = lane & 15;
    int bx   = blockIdx.x;

    if (bx < 1024) {
        int tokbase = bx * 64;
        int bb = tokbase >> 10, hwb = tokbase & 1023;
        const float* zb = z + bb * 65536 + hwb;
        int gg = bx * 4 + wave;
        int rel = wave * 16 + col;
#pragma unroll
        for (int st = 0; st < 2; st++) {
            short8 h8, l8;
#pragma unroll
            for (int j = 0; j < 8; j++) {
                int d = st * 32 + quad * 8 + j;
                float x = zb[d * 1024 + rel];
                unsigned hb = bf16_rne(x);
                h8[j] = (short)hb;
                l8[j] = (short)bf16_rne(x - __uint_as_float(hb << 16));
            }
            int base = (((gg * 2 + st) * 4 + quad) * 2 + 0) * 16 + col;
            *(short8*)(zs + base * 8)        = h8;   // hi split
            *(short8*)(zs + (base + 16) * 8) = l8;   // lo split
        }
        return;
    }
    if (bx >= 1088) {
        hist[(bx - 1088) * 256 + tid] = 0;
        if (bx == 1088 && tid < 64) loss_part[tid] = 0.f;
        return;
    }
    int c = bx - 1024, fid = wave;
    int st = fid & 1, split = fid >> 1;
    int code  = c * 16 + col;
    int dbase = st * 32 + quad * 8;
    const float* cp = cb + code * 64 + dbase;
    float4v v0 = *(const float4v*)cp;
    float4v v1 = *(const float4v*)(cp + 4);
    float xs[8] = {v0.x, v0.y, v0.z, v0.w, v1.x, v1.y, v1.z, v1.w};
    short8 frag;
    float ssq = 0.f;
#pragma unroll
    for (int j = 0; j < 8; j++) {
        float x = xs[j];
        ssq = fmaf(x, x, ssq);
        unsigned hb = bf16_rne(x);
        if (split == 0) frag[j] = (short)hb;
        else            frag[j] = (short)bf16_rne(x - __uint_as_float(hb << 16));
    }
    *(short8*)(cbf + ((c * 4 + fid) * 64 + lane) * 8) = frag;
    if (split == 0) {                    // c2 deterministic reduction (R4..R7-identical)
        ssq += __shfl_xor(ssq, 16);
        ssq += __shfl_xor(ssq, 32);
        if (quad == 0) s_c2[st][col] = ssq;
    }
    __syncthreads();
    if (tid < 16) c2h[c * 16 + tid] = -0.5f * (s_c2[0][tid] + s_c2[1][tid]);
}

// grid = 512 blocks x 512 (8 waves; 2 blocks/CU = 4 waves/SIMD). Block = 128 tokens.
// Wave w: tokens bx*128 + w*16 .. +15, ALL 64 chunks (token-split: no K-merge).
// B chunks DMA'd to LDS double-buffer (waves 0..3 issue 1 instr each); 1 barrier/chunk.
__global__ __launch_bounds__(512, 4) void argmin_kernel(
    const ushort* __restrict__ zs, const ushort* __restrict__ cbf,
    const float* __restrict__ c2h, int* __restrict__ idx_out, int* __restrict__ hist)
{
    __shared__ short8 s_b[2 * 4 * 64];   // [buf][frag][lane] 16B units = 8 KB
    __shared__ float  s_c2h[1024];       // whole -0.5*c2 table, 4 KB

    int tid  = threadIdx.x;
    int lane = tid & 63, wave = tid >> 6;
    int quad = lane >> 4, col = lane & 15;
    int bx   = blockIdx.x;
    const char* cbf_b = (const char*)cbf;

    // stage c2h (coalesced, once)
    s_c2h[tid]       = c2h[tid];
    s_c2h[tid + 512] = c2h[tid + 512];

    // A-fragments: this wave's 16 tokens, {hi,lo} x 2 K-steps (4x16B coalesced loads)
    int gg = bx * 8 + wave;
    short8 ah[2], al[2];
#pragma unroll
    for (int st = 0; st < 2; st++) {
        int base = (((gg * 2 + st) * 4 + quad) * 2 + 0) * 16 + col;
        ah[st] = *(const short8*)(zs + base * 8);
        al[st] = *(const short8*)(zs + (base + 16) * 8);
    }

    // stage chunk 0 into buf 0
    if (wave < 4)
        gl_lds16(cbf_b + (0 * 4 + wave) * 1024 + lane * 16, &s_b[wave * 64]);
    __syncthreads();

    float best[4]; int bidx[4];
#pragma unroll
    for (int r = 0; r < 4; r++) { best[r] = -1e38f; bidx[r] = 0; }

    for (int ch = 0; ch < 64; ch++) {
        int buf = ch & 1;
        if (ch < 63 && wave < 4)         // async DMA next chunk into other buffer
            gl_lds16(cbf_b + ((ch + 1) * 4 + wave) * 1024 + lane * 16,
                     &s_b[((ch + 1) & 1) * 256 + wave * 64]);

        const short8* bp = &s_b[buf * 256];
        short8 bh0 = bp[0 * 64 + lane];  // ds_read_b128, conflict-free
        short8 bh1 = bp[1 * 64 + lane];
        short8 bl0 = bp[2 * 64 + lane];
        short8 bl1 = bp[3 * 64 + lane];
        float  ini = s_c2h[ch * 16 + col];
        int   code = ch * 16 + col;

        float4v acc = {ini, ini, ini, ini};              // score = dot - c2/2 (argmax)
        acc = __builtin_amdgcn_mfma_f32_16x16x32_bf16(ah[0], bh0, acc, 0, 0, 0);
        acc = __builtin_amdgcn_mfma_f32_16x16x32_bf16(ah[1], bh1, acc, 0, 0, 0);
        acc = __builtin_amdgcn_mfma_f32_16x16x32_bf16(ah[0], bl0, acc, 0, 0, 0);
        acc = __builtin_amdgcn_mfma_f32_16x16x32_bf16(ah[1], bl1, acc, 0, 0, 0);
        acc = __builtin_amdgcn_mfma_f32_16x16x32_bf16(al[0], bh0, acc, 0, 0, 0);
        acc = __builtin_amdgcn_mfma_f32_16x16x32_bf16(al[1], bh1, acc, 0, 0, 0);
#pragma unroll
        for (int r = 0; r < 4; r++) {
            if (acc[r] > best[r]) { best[r] = acc[r]; bidx[r] = code; }  // strict >: first-min
        }
        __syncthreads();   // drains DMA (vmcnt) + guards buffer reuse
    }

    // cross-lane argmax within each quad (C row = quad*4+r, C col = code lane)
#pragma unroll
    for (int r = 0; r < 4; r++) {
        float s = best[r]; int ix = bidx[r];
#pragma unroll
        for (int m = 1; m <= 8; m <<= 1) {
            float so = __shfl_xor(s, m);
            int   io = __shfl_xor(ix, m);
            if (so > s || (so == s && io < ix)) { s = so; ix = io; }
        }
        if (col == 0) {
            int t = wave * 16 + quad * 4 + r;
            idx_out[bx * 128 + t] = ix;
            atomicAdd(&hist[ix], 1);     // one per token
        }
    }
}

// grid = 512 blocks x 256 (R7-verbatim). Block = 128 tokens: LDS row-gather + float4 stream.
__global__ __launch_bounds__(256) void output_kernel(
    const float* __restrict__ z, const float* __restrict__ cb,
    const int* __restrict__ idx, float* __restrict__ out,
    float* __restrict__ loss_part)
{
    __shared__ int    s_row[128];
    __shared__ float4 s_q4[64 * 33];
    __shared__ float  s_red[4];

    int tid = threadIdx.x, bx = blockIdx.x;
    int tokbase = bx * 128;
    int bb = tokbase >> 10, hwb = tokbase & 1023;

    if (tid < 128) s_row[tid] = idx[tokbase + tid];
    __syncthreads();

#pragma unroll
    for (int p = 0; p < 32; p++) {
        int i = p * 256 + tid;
        int t = i >> 6, d = i & 63;
        float v = cb[s_row[t] * 64 + d];
        ((float*)s_q4)[(d * 33 + (t >> 2)) * 4 + (t & 3)] = v;
    }
    __syncthreads();

    const float* zb = z   + bb * 65536 + hwb;
    float*       ob = out + bb * 65536 + hwb;
    float ls = 0.f;
#pragma unroll
    for (int p = 0; p < 8; p++) {
        int fi = p * 256 + tid;
        int d = fi >> 5, tq = fi & 31;
        float4 zv = *(const float4*)(zb + d * 1024 + tq * 4);
        float4 qv = s_q4[d * 33 + tq];
        float d0 = qv.x - zv.x, d1 = qv.y - zv.y, d2 = qv.z - zv.z, d3 = qv.w - zv.w;
        float4 ov = {zv.x + d0, zv.y + d1, zv.z + d2, zv.w + d3};   // z + (z_q - z)
        *(float4*)(ob + d * 1024 + tq * 4) = ov;
        ls += (d0 * d0 + d1 * d1) + (d2 * d2 + d3 * d3);
    }
#pragma unroll
    for (int off = 32; off; off >>= 1) ls += __shfl_down(ls, off);
    if ((tid & 63) == 0) s_red[tid >> 6] = ls;
    __syncthreads();
    if (tid == 0) {
        float v = (s_red[0] + s_red[1]) + (s_red[2] + s_red[3]);
        atomicAdd(&loss_part[bx & 63], v);
    }
}

__global__ __launch_bounds__(1024) void finalize_kernel(
    const int* __restrict__ hist, const float* __restrict__ loss_part,
    const int* __restrict__ flg, float* __restrict__ out) {
    __shared__ float red[16];
    int   k = threadIdx.x;
    float e = (float)hist[k] * (1.0f / 65536.0f);
    float v = e * logf(e + 1e-10f);
#pragma unroll
    for (int off = 32; off; off >>= 1) v += __shfl_down(v, off);
    if ((k & 63) == 0) red[k >> 6] = v;
    __syncthreads();
    if (k == 0) {
        float s = 0.f;
#pragma unroll
        for (int i = 0; i < 16; i++) s += red[i];
        out[NELEM + 1] = expf(-s);                     // perplexity

        float ls = 0.f;
        for (int i = 0; i < 64; i++) ls += loss_part[i];
        float m    = ls * (1.0f / (float)NELEM);
        out[NELEM] = (*flg) ? (0.25f * m + m) : 0.0f;  // BETA*mean + mean
    }
}

extern "C" void kernel_launch(void* const* d_in, const int* in_sizes, int n_in,
                              void* d_out, int out_size, void* d_ws, size_t ws_size,
                              hipStream_t stream) {
    const float* z   = (const float*)d_in[0];   // (64,64,32,32) f32 NCHW
    const float* cb  = (const float*)d_in[1];   // (1024,64) f32
    const int*   flg = (const int*)d_in[3];     // flg_train

    float* out = (float*)d_out;
    char*  ws  = (char*)d_ws;

    ushort* cbf       = (ushort*)(ws + WS_CBF);
    float*  c2h       = (float*)(ws + WS_C2H);
    int*    hist      = (int*)(ws + WS_HIST);
    float*  loss_part = (float*)(ws + WS_LOSS);
    int*    idx       = (int*)(ws + WS_IDX);
    ushort* zs        = (ushort*)d_out;          // scratch inside d_out (see header)

    prep_kernel<<<1092, 256, 0, stream>>>(z, cb, zs, cbf, c2h, hist, loss_part);
    argmin_kernel<<<512, 512, 0, stream>>>(zs, cbf, c2h, idx, hist);
    output_kernel<<<512, 256, 0, stream>>>(z, cb, idx, out, loss_part);
    finalize_kernel<<<1, 1024, 0, stream>>>(hist, loss_part, flg, out);
}

// Round 9
// 144.317 us; speedup vs baseline: 1.0869x; 1.0869x over previous
//
#include <hip/hip_runtime.h>

// VQ-VAE quantizer, MI355X (gfx950). B=64, C=D=64, H=32, W=32 -> N=65536 tokens, K=1024 codes.
// Round 9: fix R8's barrier-drain bug. R8 issued next-chunk DMA then hit __syncthreads 6
// MFMAs later -- the barrier's implicit vmcnt(0) drain waited for the JUST-issued DMA ->
// zero overlap, serial L2 latency x64 chunks (argmin 71.7us, MfmaUtil 13%).
//   argmin: 512 blocks x 512 thr, block = 128 tokens, wave = 16 tokens, all 64 chunks.
//           B staged in 8-chunk PANELS (32 KB) double-buffered: issue panel p+1 DMA ->
//           consume panel p (48 MFMA/wave ~= 3,700 cyc cover) -> barrier. DMA (~585 cyc
//           of L2 BW) fully hidden; 8 barriers total instead of 64.
//           Per-SIMD: 4 waves x 48 MFMA x 19.4 cyc/panel -> MFMA-bound, floor 12.4us.
//   prep/output/finalize: R7-verbatim (proven).
// Distance math bit-identical to R4..R8 (absmax 2.394531): 3-product split-bf16, same
// MFMA order, ascending-chunk strict-> ties, lowest-code-on-tie cross-lane.
// Outputs (flat): z_q [4194304] f32 NCHW, loss [1], perplexity [1].

typedef __attribute__((ext_vector_type(8))) short short8;   // 8 bf16 (4 VGPRs)
typedef __attribute__((ext_vector_type(4))) float float4v;  // MFMA C/D frag

#define NELEM 4194304

// ---- workspace layout (bytes) ----
#define WS_CBF   0        // ushort[131072]: packed split-bf16 codebook, B-frag order (256 KB)
#define WS_C2H   262144   // f32 c2h[1024] = -0.5*||c||^2
#define WS_HIST  266240   // i32 hist[1024]
#define WS_LOSS  270336   // f32 loss_part[64]
#define WS_IDX   270592   // i32 idx[65536]
// zs (split-bf16 z, 16,777,216 B) lives in d_out (16,777,224 B): consumed by argmin,
// then overwritten by output_kernel (stream-ordered).

__device__ __forceinline__ unsigned bf16_rne(float x) {
    unsigned u = __float_as_uint(x);
    return (u + 0x7fffu + ((u >> 16) & 1u)) >> 16;
}

__device__ __forceinline__ void gl_lds16(const void* g, void* l) {
    // async global->LDS DMA, 16B/lane; LDS dst = uniform base + lane*16 (HW scatter)
    __builtin_amdgcn_global_load_lds(
        (const __attribute__((address_space(1))) unsigned*)g,
        (__attribute__((address_space(3))) unsigned*)l, 16, 0, 0);
}

// zs layout (short8 units): id = (((gg*2 + st)*4 + quad)*2 + split)*16 + col
// cbf layout (bytes): (chunk*4 + fid)*1024 + lane*16, fid = split*2 + st.

// grid = 1092 blocks x 256 (R7-verbatim):
//   0..1023 zsplit; 1024..1087 pack codebook chunk + c2; 1088..1091 zero hist/loss.
__global__ __launch_bounds__(256) void prep_kernel(
    const float* __restrict__ z, const float* __restrict__ cb,
    ushort* __restrict__ zs, ushort* __restrict__ cbf, float* __restrict__ c2h,
    int* __restrict__ hist, float* __restrict__ loss_part)
{
    __shared__ float s_c2[2][16];
    int tid  = threadIdx.x;
    int lane = tid & 63, wave = tid >> 6;
    int quad = lane >> 4, col = lane & 15;
    int bx   = blockIdx.x;

    if (bx < 1024) {
        int tokbase = bx * 64;
        int bb = tokbase >> 10, hwb = tokbase & 1023;
        const float* zb = z + bb * 65536 + hwb;
        int gg = bx * 4 + wave;
        int rel = wave * 16 + col;
#pragma unroll
        for (int st = 0; st < 2; st++) {
            short8 h8, l8;
#pragma unroll
            for (int j = 0; j < 8; j++) {
                int d = st * 32 + quad * 8 + j;
                float x = zb[d * 1024 + rel];
                unsigned hb = bf16_rne(x);
                h8[j] = (short)hb;
                l8[j] = (short)bf16_rne(x - __uint_as_float(hb << 16));
            }
            int base = (((gg * 2 + st) * 4 + quad) * 2 + 0) * 16 + col;
            *(short8*)(zs + base * 8)        = h8;   // hi split
            *(short8*)(zs + (base + 16) * 8) = l8;   // lo split
        }
        return;
    }
    if (bx >= 1088) {
        hist[(bx - 1088) * 256 + tid] = 0;
        if (bx == 1088 && tid < 64) loss_part[tid] = 0.f;
        return;
    }
    int c = bx - 1024, fid = wave;
    int st = fid & 1, split = fid >> 1;
    int code  = c * 16 + col;
    int dbase = st * 32 + quad * 8;
    const float* cp = cb + code * 64 + dbase;
    float4v v0 = *(const float4v*)cp;
    float4v v1 = *(const float4v*)(cp + 4);
    float xs[8] = {v0.x, v0.y, v0.z, v0.w, v1.x, v1.y, v1.z, v1.w};
    short8 frag;
    float ssq = 0.f;
#pragma unroll
    for (int j = 0; j < 8; j++) {
        float x = xs[j];
        ssq = fmaf(x, x, ssq);
        unsigned hb = bf16_rne(x);
        if (split == 0) frag[j] = (short)hb;
        else            frag[j] = (short)bf16_rne(x - __uint_as_float(hb << 16));
    }
    *(short8*)(cbf + ((c * 4 + fid) * 64 + lane) * 8) = frag;
    if (split == 0) {                    // c2 deterministic reduction (R4..R8-identical)
        ssq += __shfl_xor(ssq, 16);
        ssq += __shfl_xor(ssq, 32);
        if (quad == 0) s_c2[st][col] = ssq;
    }
    __syncthreads();
    if (tid < 16) c2h[c * 16 + tid] = -0.5f * (s_c2[0][tid] + s_c2[1][tid]);
}

// grid = 512 blocks x 512 (8 waves; 2 blocks/CU, 4 waves/SIMD). Block = 128 tokens.
// Wave w: tokens bx*128 + w*16 .. +15, all 64 chunks. B staged in 8-chunk panels,
// double-buffered; DMA issued BEFORE consume, barrier AFTER -> drain fully covered.
__global__ __launch_bounds__(512, 4) void argmin_kernel(
    const ushort* __restrict__ zs, const ushort* __restrict__ cbf,
    const float* __restrict__ c2h, int* __restrict__ idx_out, int* __restrict__ hist)
{
    __shared__ short8 s_b[2 * 32 * 64];  // [buf][frag(8ch x 4)][lane] 16B units = 64 KB
    __shared__ float  s_c2h[1024];       // whole -0.5*c2 table, 4 KB

    int tid  = threadIdx.x;
    int lane = tid & 63, wave = tid >> 6;
    int quad = lane >> 4, col = lane & 15;
    int bx   = blockIdx.x;
    const char* cbf_b = (const char*)cbf;

    // stage c2h (coalesced, once; published by the prologue barrier)
    s_c2h[tid]       = c2h[tid];
    s_c2h[tid + 512] = c2h[tid + 512];

    // A-fragments: this wave's 16 tokens, {hi,lo} x 2 K-steps (4x16B coalesced loads)
    int gg = bx * 8 + wave;
    short8 ah[2], al[2];
#pragma unroll
    for (int st = 0; st < 2; st++) {
        int base = (((gg * 2 + st) * 4 + quad) * 2 + 0) * 16 + col;
        ah[st] = *(const short8*)(zs + base * 8);
        al[st] = *(const short8*)(zs + (base + 16) * 8);
    }

    // prologue: stage panel 0 (32 frags, 4 per wave) into buf 0, then drain
#pragma unroll
    for (int i = 0; i < 4; i++) {
        int fi = wave * 4 + i;
        gl_lds16(cbf_b + fi * 1024 + lane * 16, &s_b[fi * 64]);
    }
    __syncthreads();

    float best[4]; int bidx[4];
#pragma unroll
    for (int r = 0; r < 4; r++) { best[r] = -1e38f; bidx[r] = 0; }

    for (int p = 0; p < 8; p++) {        // 8 panels x 8 chunks
        int buf = p & 1;
        if (p < 7) {                     // issue next panel's DMA FIRST (overlap window)
            int nb = (p + 1) & 1;
#pragma unroll
            for (int i = 0; i < 4; i++) {
                int fi = wave * 4 + i;
                gl_lds16(cbf_b + ((p + 1) * 32 + fi) * 1024 + lane * 16,
                         &s_b[(nb * 32 + fi) * 64]);
            }
        }
        // consume panel p: 8 chunks x 6 MFMA (~3,700 cyc/SIMD of cover for the DMA)
#pragma unroll
        for (int cl = 0; cl < 8; cl++) {
            int ch = p * 8 + cl;
            const short8* bp = &s_b[(buf * 32 + cl * 4) * 64];
            short8 bh0 = bp[lane];            // ds_read_b128, 2-way aliasing (free)
            short8 bh1 = bp[64 + lane];
            short8 bl0 = bp[128 + lane];
            short8 bl1 = bp[192 + lane];
            float  ini = s_c2h[ch * 16 + col];
            int   code = ch * 16 + col;

            float4v acc = {ini, ini, ini, ini};          // score = dot - c2/2 (argmax)
            acc = __builtin_amdgcn_mfma_f32_16x16x32_bf16(ah[0], bh0, acc, 0, 0, 0);
            acc = __builtin_amdgcn_mfma_f32_16x16x32_bf16(ah[1], bh1, acc, 0, 0, 0);
            acc = __builtin_amdgcn_mfma_f32_16x16x32_bf16(ah[0], bl0, acc, 0, 0, 0);
            acc = __builtin_amdgcn_mfma_f32_16x16x32_bf16(ah[1], bl1, acc, 0, 0, 0);
            acc = __builtin_amdgcn_mfma_f32_16x16x32_bf16(al[0], bh0, acc, 0, 0, 0);
            acc = __builtin_amdgcn_mfma_f32_16x16x32_bf16(al[1], bh1, acc, 0, 0, 0);
#pragma unroll
            for (int r = 0; r < 4; r++) {
                if (acc[r] > best[r]) { best[r] = acc[r]; bidx[r] = code; }  // strict >
            }
        }
        __syncthreads();   // drains panel p+1 DMA (covered) + guards buf reuse
    }

    // cross-lane argmax within each quad (C row = quad*4+r, C col = code lane)
#pragma unroll
    for (int r = 0; r < 4; r++) {
        float s = best[r]; int ix = bidx[r];
#pragma unroll
        for (int m = 1; m <= 8; m <<= 1) {
            float so = __shfl_xor(s, m);
            int   io = __shfl_xor(ix, m);
            if (so > s || (so == s && io < ix)) { s = so; ix = io; }
        }
        if (col == 0) {
            int t = wave * 16 + quad * 4 + r;
            idx_out[bx * 128 + t] = ix;
            atomicAdd(&hist[ix], 1);     // one per token
        }
    }
}

// grid = 512 blocks x 256 (R7-verbatim). Block = 128 tokens: LDS row-gather + float4 stream.
__global__ __launch_bounds__(256) void output_kernel(
    const float* __restrict__ z, const float* __restrict__ cb,
    const int* __restrict__ idx, float* __restrict__ out,
    float* __restrict__ loss_part)
{
    __shared__ int    s_row[128];
    __shared__ float4 s_q4[64 * 33];
    __shared__ float  s_red[4];

    int tid = threadIdx.x, bx = blockIdx.x;
    int tokbase = bx * 128;
    int bb = tokbase >> 10, hwb = tokbase & 1023;

    if (tid < 128) s_row[tid] = idx[tokbase + tid];
    __syncthreads();

#pragma unroll
    for (int p = 0; p < 32; p++) {
        int i = p * 256 + tid;
        int t = i >> 6, d = i & 63;
        float v = cb[s_row[t] * 64 + d];
        ((float*)s_q4)[(d * 33 + (t >> 2)) * 4 + (t & 3)] = v;
    }
    __syncthreads();

    const float* zb = z   + bb * 65536 + hwb;
    float*       ob = out + bb * 65536 + hwb;
    float ls = 0.f;
#pragma unroll
    for (int p = 0; p < 8; p++) {
        int fi = p * 256 + tid;
        int d = fi >> 5, tq = fi & 31;
        float4 zv = *(const float4*)(zb + d * 1024 + tq * 4);
        float4 qv = s_q4[d * 33 + tq];
        float d0 = qv.x - zv.x, d1 = qv.y - zv.y, d2 = qv.z - zv.z, d3 = qv.w - zv.w;
        float4 ov = {zv.x + d0, zv.y + d1, zv.z + d2, zv.w + d3};   // z + (z_q - z)
        *(float4*)(ob + d * 1024 + tq * 4) = ov;
        ls += (d0 * d0 + d1 * d1) + (d2 * d2 + d3 * d3);
    }
#pragma unroll
    for (int off = 32; off; off >>= 1) ls += __shfl_down(ls, off);
    if ((tid & 63) == 0) s_red[tid >> 6] = ls;
    __syncthreads();
    if (tid == 0) {
        float v = (s_red[0] + s_red[1]) + (s_red[2] + s_red[3]);
        atomicAdd(&loss_part[bx & 63], v);
    }
}

__global__ __launch_bounds__(1024) void finalize_kernel(
    const int* __restrict__ hist, const float* __restrict__ loss_part,
    const int* __restrict__ flg, float* __restrict__ out) {
    __shared__ float red[16];
    int   k = threadIdx.x;
    float e = (float)hist[k] * (1.0f / 65536.0f);
    float v = e * logf(e + 1e-10f);
#pragma unroll
    for (int off = 32; off; off >>= 1) v += __shfl_down(v, off);
    if ((k & 63) == 0) red[k >> 6] = v;
    __syncthreads();
    if (k == 0) {
        float s = 0.f;
#pragma unroll
        for (int i = 0; i < 16; i++) s += red[i];
        out[NELEM + 1] = expf(-s);                     // perplexity

        float ls = 0.f;
        for (int i = 0; i < 64; i++) ls += loss_part[i];
        float m    = ls * (1.0f / (float)NELEM);
        out[NELEM] = (*flg) ? (0.25f * m + m) : 0.0f;  // BETA*mean + mean
    }
}

extern "C" void kernel_launch(void* const* d_in, const int* in_sizes, int n_in,
                              void* d_out, int out_size, void* d_ws, size_t ws_size,
                              hipStream_t stream) {
    const float* z   = (const float*)d_in[0];   // (64,64,32,32) f32 NCHW
    const float* cb  = (const float*)d_in[1];   // (1024,64) f32
    const int*   flg = (const int*)d_in[3];     // flg_train

    float* out = (float*)d_out;
    char*  ws  = (char*)d_ws;

    ushort* cbf       = (ushort*)(ws + WS_CBF);
    float*  c2h       = (float*)(ws + WS_C2H);
    int*    hist      = (int*)(ws + WS_HIST);
    float*  loss_part = (float*)(ws + WS_LOSS);
    int*    idx       = (int*)(ws + WS_IDX);
    ushort* zs        = (ushort*)d_out;          // scratch inside d_out (see header)

    prep_kernel<<<1092, 256, 0, stream>>>(z, cb, zs, cbf, c2h, hist, loss_part);
    argmin_kernel<<<512, 512, 0, stream>>>(zs, cbf, c2h, idx, hist);
    output_kernel<<<512, 256, 0, stream>>>(z, cb, idx, out, loss_part);
    finalize_kernel<<<1, 1024, 0, stream>>>(hist, loss_part, flg, out);
}